// Round 2
// baseline (965.598 us; speedup 1.0000x reference)
//
#include <hip/hip_runtime.h>

// ---------------------------------------------------------------------------
// PerceiverAttention on MI355X.
// B=8 T=8 N=1024 NL=64 DIM=1024 H=16 DH=64, SCALE=8 (post-softmax divide).
// Strategy: bf16 MFMA for all GEMMs (kv GEMM = 292 of 327 GFLOP total).
// R1: fix attn Q/K staging (was loading only cols 0..31); 1-D grid + bijective
//     XCD swizzle (m204) on gemm_tn and attn.
// ---------------------------------------------------------------------------

typedef __attribute__((ext_vector_type(8))) short s8v;   // 8 x bf16 bits (4 VGPR)
typedef __attribute__((ext_vector_type(4))) float f4v;   // MFMA accumulator

#define BT_ 64
#define NKV 1088
#define NKV_PAD 1152

__device__ __forceinline__ ushort f2bf(float f){
  union { float f; unsigned u; } v; v.f = f;
  unsigned r = v.u + 0x7FFFu + ((v.u >> 16) & 1u);   // RNE
  return (ushort)(r >> 16);
}

__device__ __forceinline__ void gload_lds16(const ushort* g, ushort* l){
  __builtin_amdgcn_global_load_lds((const __attribute__((address_space(1))) void*)g,
                                   (__attribute__((address_space(3))) void*)l,
                                   16, 0, 0);
}

// m204 bijective XCD swizzle: consecutive output ids land on one XCD chunk.
__device__ __forceinline__ int xcd_swizzle(int orig, int nwg){
  int q = nwg >> 3, r = nwg & 7;
  int xcd = orig & 7, idx = orig >> 3;
  return (xcd < r ? xcd*(q+1) : r*(q+1) + (xcd-r)*q) + idx;
}

// ---------------------------------------------------------------------------
// LayerNorm of media (rows 0..1023 per bt) and latents (rows 1024..1087),
// written as bf16 into lnA [BT][1152][1024] (rows 1088..1151 left as garbage —
// GEMM reads them in-bounds, stores are row-guarded; 0xAA bf16 is a tiny
// finite value, no NaN/Inf).
// ---------------------------------------------------------------------------
__global__ __launch_bounds__(256)
void ln_kernel(const float* __restrict__ media, const float* __restrict__ latents,
               const float* __restrict__ g_m, const float* __restrict__ b_m,
               const float* __restrict__ g_l, const float* __restrict__ b_l,
               ushort* __restrict__ lnA){
  int g = blockIdx.x;
  int bt = g / 1088, rr = g - bt * 1088;
  const float* src; const float* gam; const float* bet;
  if (rr < 1024){ src = media   + ((long)bt*1024 + rr)        *1024; gam = g_m; bet = b_m; }
  else          { src = latents + ((long)bt*64   + (rr-1024)) *1024; gam = g_l; bet = b_l; }
  int tid = threadIdx.x;
  float4 x = ((const float4*)src)[tid];
  float s  = x.x + x.y + x.z + x.w;
  float s2 = x.x*x.x + x.y*x.y + x.z*x.z + x.w*x.w;
  #pragma unroll
  for (int off = 32; off > 0; off >>= 1){
    s  += __shfl_down(s,  off);
    s2 += __shfl_down(s2, off);
  }
  __shared__ float ps[4], ps2[4];
  if ((tid & 63) == 0){ ps[tid>>6] = s; ps2[tid>>6] = s2; }
  __syncthreads();
  float tot  = ps[0]+ps[1]+ps[2]+ps[3];
  float tot2 = ps2[0]+ps2[1]+ps2[2]+ps2[3];
  float mean = tot * (1.f/1024.f);
  float var  = tot2 * (1.f/1024.f) - mean*mean;
  float rinv = rsqrtf(var + 1e-5f);
  float4 gm4 = ((const float4*)gam)[tid];
  float4 bt4 = ((const float4*)bet)[tid];
  ushort4 o;
  o.x = f2bf((x.x-mean)*rinv*gm4.x + bt4.x);
  o.y = f2bf((x.y-mean)*rinv*gm4.y + bt4.y);
  o.z = f2bf((x.z-mean)*rinv*gm4.z + bt4.z);
  o.w = f2bf((x.w-mean)*rinv*gm4.w + bt4.w);
  *(ushort4*)&lnA[((long)bt*NKV_PAD + rr)*1024 + tid*4] = o;
}

// ---------------------------------------------------------------------------
// Transpose-cast fp32 weight W[K][N] -> bf16 WT[N][K].
// ---------------------------------------------------------------------------
__global__ __launch_bounds__(256)
void transpose_cast(const float* __restrict__ W, ushort* __restrict__ WT, int K, int N){
  __shared__ float tile[32][33];
  int n0 = blockIdx.x*32, k0 = blockIdx.y*32;
  int tx = threadIdx.x & 31, ty = threadIdx.x >> 5;  // 32 x 8
  #pragma unroll
  for (int i = 0; i < 32; i += 8) tile[ty+i][tx] = W[(long)(k0+ty+i)*N + n0+tx];
  __syncthreads();
  #pragma unroll
  for (int i = 0; i < 32; i += 8) WT[(long)(n0+ty+i)*K + k0+tx] = f2bf(tile[tx][ty+i]);
}

// ---------------------------------------------------------------------------
// Batched bf16 GEMM, m97-style: BM=BN=128, BK=32, 256 threads (2x2 waves,
// 64x64 per wave, 4x4 frags of 16x16x32). A row-major [.,K=1024], B given
// pre-transposed [N][K]. 1-D grid, XCD-swizzled. Row-guarded stores.
// ---------------------------------------------------------------------------
template<int STORE_BF16>
__global__ __launch_bounds__(256)
void gemm_tn(const ushort* __restrict__ A, long strideAbatch,
             const ushort* __restrict__ BT,
             void* __restrict__ C, long strideCbatch,
             int Mvalid, int N, int tiles_n, int tiles_per_batch){
  constexpr int K = 1024;
  __shared__ ushort As[128*32];
  __shared__ ushort Bs[128*32];
  int wgid = xcd_swizzle(blockIdx.x, gridDim.x);
  int batch = wgid / tiles_per_batch;
  int tile  = wgid - batch*tiles_per_batch;
  int tm = tile / tiles_n, tn = tile % tiles_n;
  const ushort* Ab = A  + (long)batch*strideAbatch + (long)tm*128*K;
  const ushort* Bb = BT + (long)tn*128*K;
  int tid = threadIdx.x;
  int lane = tid & 63, wave = tid >> 6;
  int wm = wave >> 1, wn = wave & 1;
  f4v acc[4][4] = {};

  for (int kt = 0; kt < K/32; ++kt){
    // stage A (8KB) + B (8KB): 4 x 16B per thread; LDS dest = wave-uniform
    // base + lane*16 (slot algebra: base_elem + lane*8 == slot*8).
    #pragma unroll
    for (int r = 0; r < 4; ++r){
      int slot = r*256 + tid;
      const ushort* g; ushort* l;
      if (slot < 512){
        int row = slot >> 2, seg = slot & 3;
        g = Ab + (long)row*K + kt*32 + seg*8;
        l = &As[(r*256 + wave*64)*8];
      } else {
        int s2 = slot - 512;
        int row = s2 >> 2, seg = s2 & 3;
        g = Bb + (long)row*K + kt*32 + seg*8;
        l = &Bs[((r-2)*256 + wave*64)*8];
      }
      gload_lds16(g, l);
    }
    __syncthreads();   // drains vmcnt -> tiles visible
    s8v av[4], bv[4];
    #pragma unroll
    for (int m = 0; m < 4; ++m)
      av[m] = *(const s8v*)&As[(wm*64 + m*16 + (lane&15))*32 + (lane>>4)*8];
    #pragma unroll
    for (int n = 0; n < 4; ++n)
      bv[n] = *(const s8v*)&Bs[(wn*64 + n*16 + (lane&15))*32 + (lane>>4)*8];
    #pragma unroll
    for (int m = 0; m < 4; ++m)
      #pragma unroll
      for (int n = 0; n < 4; ++n)
        acc[m][n] = __builtin_amdgcn_mfma_f32_16x16x32_bf16(av[m], bv[n], acc[m][n], 0, 0, 0);
    __syncthreads();   // reads done before next stage overwrites
  }

  long cb = (long)batch*strideCbatch;
  #pragma unroll
  for (int m = 0; m < 4; ++m){
    int row0 = tm*128 + wm*64 + m*16 + ((lane>>4)<<2);
    #pragma unroll
    for (int n = 0; n < 4; ++n){
      int col = tn*128 + wn*64 + n*16 + (lane&15);
      #pragma unroll
      for (int j = 0; j < 4; ++j){
        int row = row0 + j;
        if (row < Mvalid){
          if (STORE_BF16) ((ushort*)C)[cb + (long)row*N + col] = f2bf(acc[m][n][j]);
          else            ((float*) C)[cb + (long)row*N + col] = acc[m][n][j];
        }
      }
    }
  }
}

// ---------------------------------------------------------------------------
// Fused attention per (b,t,h): Q[64,64] x K[1088,64]^T -> online softmax ->
// P x V[1088,64]. 4 waves, each owns 16 q-rows. Padded [64][72] LDS tiles.
// ---------------------------------------------------------------------------
__global__ __launch_bounds__(256)
void attn_kernel(const ushort* __restrict__ qbuf, const ushort* __restrict__ kv,
                 ushort* __restrict__ aout){
  __shared__ ushort Qs [64*72];
  __shared__ ushort Ks [64*72];
  __shared__ ushort VTs[64*72];
  __shared__ ushort Ps [64*72];
  int blk = xcd_swizzle(blockIdx.x, gridDim.x);  // 16 consecutive share one bt's KV
  int bt = blk >> 4, h = blk & 15;
  int tid = threadIdx.x, lane = tid & 63, wave = tid >> 6;

  { // stage Q [64 rows][64 cols]: thread t -> row t>>2, cols (t&3)*16 .. +15
    int r = tid >> 2, c0 = (tid & 3) * 16;
    const ushort* src = &qbuf[((long)bt*64 + r)*1024 + h*64 + c0];
    *(s8v*)&Qs[r*72 + c0]     = *(const s8v*)(src);
    *(s8v*)&Qs[r*72 + c0 + 8] = *(const s8v*)(src + 8);
  }
  float m_[4], l_[4];
  f4v accO[4] = {};
  #pragma unroll
  for (int j = 0; j < 4; ++j){ m_[j] = -1e30f; l_[j] = 0.f; }
  const long kvbase = (long)bt*NKV*2048;

  for (int t0 = 0; t0 < NKV; t0 += 64){
    __syncthreads();  // previous-iter reads done (also publishes Q on iter 0)
    { // stage K tile [64][64], full 64 cols
      int r = tid >> 2, c0 = (tid & 3) * 16;
      const ushort* src = &kv[kvbase + (long)(t0+r)*2048 + h*64 + c0];
      *(s8v*)&Ks[r*72 + c0]     = *(const s8v*)(src);
      *(s8v*)&Ks[r*72 + c0 + 8] = *(const s8v*)(src + 8);
    }
    { // stage V^T: VTs[dh][kk]
      int kk = tid & 63, dg = tid >> 6;
      s8v v0 = *(const s8v*)&kv[kvbase + (long)(t0+kk)*2048 + 1024 + h*64 + dg*16];
      s8v v1 = *(const s8v*)&kv[kvbase + (long)(t0+kk)*2048 + 1024 + h*64 + dg*16 + 8];
      #pragma unroll
      for (int e = 0; e < 8; ++e) VTs[(dg*16+e)  *72 + kk] = v0[e];
      #pragma unroll
      for (int e = 0; e < 8; ++e) VTs[(dg*16+8+e)*72 + kk] = v1[e];
    }
    __syncthreads();

    // S = Q K^T  (this wave's 16 q-rows x 64 kk)
    f4v s[4] = {};
    s8v aq0 = *(const s8v*)&Qs[(wave*16 + (lane&15))*72 +      (lane>>4)*8];
    s8v aq1 = *(const s8v*)&Qs[(wave*16 + (lane&15))*72 + 32 + (lane>>4)*8];
    #pragma unroll
    for (int n = 0; n < 4; ++n){
      s8v bk0 = *(const s8v*)&Ks[(n*16 + (lane&15))*72 +      (lane>>4)*8];
      s8v bk1 = *(const s8v*)&Ks[(n*16 + (lane&15))*72 + 32 + (lane>>4)*8];
      s[n] = __builtin_amdgcn_mfma_f32_16x16x32_bf16(aq0, bk0, s[n], 0, 0, 0);
      s[n] = __builtin_amdgcn_mfma_f32_16x16x32_bf16(aq1, bk1, s[n], 0, 0, 0);
    }

    // online softmax over this tile; row q = wave*16 + (lane>>4)*4 + j
    #pragma unroll
    for (int j = 0; j < 4; ++j){
      float v = fmaxf(fmaxf(s[0][j], s[1][j]), fmaxf(s[2][j], s[3][j]));
      #pragma unroll
      for (int off = 1; off < 16; off <<= 1) v = fmaxf(v, __shfl_xor(v, off));
      float mn = fmaxf(m_[j], v);
      float sc = __expf(m_[j] - mn);
      m_[j] = mn;
      float ss = 0.f;
      #pragma unroll
      for (int n = 0; n < 4; ++n){ float pv = __expf(s[n][j] - mn); s[n][j] = pv; ss += pv; }
      #pragma unroll
      for (int off = 1; off < 16; off <<= 1) ss += __shfl_xor(ss, off);
      l_[j] = l_[j]*sc + ss;
      #pragma unroll
      for (int dn = 0; dn < 4; ++dn) accO[dn][j] *= sc;
    }

    // P -> LDS (wave-private rows), re-layout for PV A-operand
    #pragma unroll
    for (int n = 0; n < 4; ++n)
      #pragma unroll
      for (int j = 0; j < 4; ++j)
        Ps[(wave*16 + ((lane>>4)<<2) + j)*72 + n*16 + (lane&15)] = f2bf(s[n][j]);

    // O += P V
    s8v pa0 = *(const s8v*)&Ps[(wave*16 + (lane&15))*72 +      (lane>>4)*8];
    s8v pa1 = *(const s8v*)&Ps[(wave*16 + (lane&15))*72 + 32 + (lane>>4)*8];
    #pragma unroll
    for (int dn = 0; dn < 4; ++dn){
      s8v bv0 = *(const s8v*)&VTs[(dn*16 + (lane&15))*72 +      (lane>>4)*8];
      s8v bv1 = *(const s8v*)&VTs[(dn*16 + (lane&15))*72 + 32 + (lane>>4)*8];
      accO[dn] = __builtin_amdgcn_mfma_f32_16x16x32_bf16(pa0, bv0, accO[dn], 0, 0, 0);
      accO[dn] = __builtin_amdgcn_mfma_f32_16x16x32_bf16(pa1, bv1, accO[dn], 0, 0, 0);
    }
  }

  // epilogue: O / l / SCALE(=8), bf16 into padded attn_out [BT][128][1024]
  #pragma unroll
  for (int dn = 0; dn < 4; ++dn)
    #pragma unroll
    for (int j = 0; j < 4; ++j){
      int q = wave*16 + ((lane>>4)<<2) + j;
      float o = accO[dn][j] / (l_[j] * 8.0f);
      aout[((long)bt*128 + q)*1024 + h*64 + dn*16 + (lane&15)] = f2bf(o);
    }
}

// ---------------------------------------------------------------------------
// Workspace layout (bytes): total ~470 MB
// ---------------------------------------------------------------------------
static constexpr size_t SZ_LNA   = (size_t)BT_*NKV_PAD*1024*2;   // 150,994,944
static constexpr size_t SZ_KV    = (size_t)BT_*NKV*2048*2;       // 285,212,672
static constexpr size_t SZ_Q     = (size_t)BT_*64*1024*2;        //   8,388,608
static constexpr size_t SZ_AO    = (size_t)BT_*128*1024*2;       //  16,777,216
static constexpr size_t SZ_WQT   = (size_t)1024*1024*2;
static constexpr size_t SZ_WKVT  = (size_t)2048*1024*2;

extern "C" void kernel_launch(void* const* d_in, const int* in_sizes, int n_in,
                              void* d_out, int out_size, void* d_ws, size_t ws_size,
                              hipStream_t stream){
  const float* media   = (const float*)d_in[0];
  const float* latents = (const float*)d_in[1];
  const float* g_m     = (const float*)d_in[2];
  const float* b_m     = (const float*)d_in[3];
  const float* g_l     = (const float*)d_in[4];
  const float* b_l     = (const float*)d_in[5];
  const float* Wq      = (const float*)d_in[6];
  const float* Wkv     = (const float*)d_in[7];
  const float* Wout    = (const float*)d_in[8];

  char* ws = (char*)d_ws;
  ushort* lnA   = (ushort*)(ws);
  ushort* kvb   = (ushort*)(ws + SZ_LNA);
  ushort* qb    = (ushort*)(ws + SZ_LNA + SZ_KV);
  ushort* aob   = (ushort*)(ws + SZ_LNA + SZ_KV + SZ_Q);
  ushort* WqT   = (ushort*)(ws + SZ_LNA + SZ_KV + SZ_Q + SZ_AO);
  ushort* WkvT  = (ushort*)(ws + SZ_LNA + SZ_KV + SZ_Q + SZ_AO + SZ_WQT);
  ushort* WoutT = (ushort*)(ws + SZ_LNA + SZ_KV + SZ_Q + SZ_AO + SZ_WQT + SZ_WKVT);

  ln_kernel<<<BT_*1088, 256, 0, stream>>>(media, latents, g_m, b_m, g_l, b_l, lnA);
  transpose_cast<<<dim3(1024/32, 1024/32), 256, 0, stream>>>(Wq,   WqT,   1024, 1024);
  transpose_cast<<<dim3(2048/32, 1024/32), 256, 0, stream>>>(Wkv,  WkvT,  1024, 2048);
  transpose_cast<<<dim3(1024/32, 1024/32), 256, 0, stream>>>(Wout, WoutT, 1024, 1024);

  // kv = lnA(1088 rows) @ Wkv -> bf16 [BT][1088][2048]; 9x16 tiles x 64 batches
  gemm_tn<1><<<9*16*BT_, 256, 0, stream>>>(lnA, (long)NKV_PAD*1024, WkvT,
                                           kvb, (long)NKV*2048, NKV, 2048, 16, 9*16);
  // q = latents_ln @ Wq -> bf16 [BT][64][1024] (M padded to 128, store-guarded)
  gemm_tn<1><<<8*BT_, 256, 0, stream>>>(lnA + 1024*1024, (long)NKV_PAD*1024, WqT,
                                        qb, (long)64*1024, 64, 1024, 8, 8);

  attn_kernel<<<BT_*16, 256, 0, stream>>>(qb, kvb, aob);

  // out = attn_out @ Wout -> f32 d_out [BT][64][1024]
  gemm_tn<0><<<8*BT_, 256, 0, stream>>>(aob, (long)128*1024, WoutT,
                                        d_out, (long)64*1024, 64, 1024, 8, 8);
}